// Round 12
// baseline (2241.295 us; speedup 1.0000x reference)
//
#include <hip/hip_runtime.h>
#include <hip/hip_bf16.h>
#include <float.h>
#include <math.h>

#define NB 4
#define NN 8192
#define FF 64
#define MM 2048
#define KK 32
#define HH 64

#define FT 512          // fps threads (8 waves)

typedef float v2f __attribute__((ext_vector_type(2)));
typedef unsigned long long u64;

// forced packed-FP32 VOP3P ops (gfx90a+/gfx950); 64-bit operands -> VGPR pairs
__device__ __forceinline__ v2f pk_add(v2f a, v2f b) {
    v2f r; asm("v_pk_add_f32 %0, %1, %2" : "=v"(r) : "v"(a), "v"(b)); return r;
}
__device__ __forceinline__ v2f pk_mul(v2f a, v2f b) {
    v2f r; asm("v_pk_mul_f32 %0, %1, %2" : "=v"(r) : "v"(a), "v"(b)); return r;
}

// 64-bit packed argmax DPP step: integer max on ((v_bits<<32)|(8191-idx))
// == max value, tie -> lower index (v >= 0 so float bit order == value order).
// identity old = 0. (validated round 8)
#define DPP64_STEP(b, ctrl, rmask)                                              \
    {                                                                           \
        const unsigned int _lo = (unsigned int)(b);                             \
        const unsigned int _hi = (unsigned int)((b) >> 32);                     \
        const unsigned int _olo = (unsigned int)__builtin_amdgcn_update_dpp(    \
            0, (int)_lo, (ctrl), (rmask), 0xf, false);                          \
        const unsigned int _ohi = (unsigned int)__builtin_amdgcn_update_dpp(    \
            0, (int)_hi, (ctrl), (rmask), 0xf, false);                          \
        const u64 _o = (((u64)_ohi) << 32) | _olo;                              \
        if (_o > (b)) (b) = _o;                                                 \
    }
#define DPP64_REDUCE(b)            \
    DPP64_STEP(b, 0x111, 0xf)      \
    DPP64_STEP(b, 0x112, 0xf)      \
    DPP64_STEP(b, 0x114, 0xf)      \
    DPP64_STEP(b, 0x118, 0xf)      \
    DPP64_STEP(b, 0x142, 0xa)      \
    DPP64_STEP(b, 0x143, 0xc)

// ---------------- Kernel 1: exact FPS, pk-math + single-barrier tail ----------------
__global__ __launch_bounds__(FT) void fps_kernel(
    const float* __restrict__ pos,
    int* __restrict__ samp,
    float* __restrict__ centers_out,
    float* __restrict__ batch_out)
{
#pragma clang fp contract(off)
    __shared__ float4 pts4[NN];          // natural order; winner-fetch only (128 KB)
    __shared__ u64 wsel[3];              // rotating block-winner accumulators

    const int b = blockIdx.x;
    const float* pb = pos + (size_t)b * NN * 3;
    const int tid = threadIdx.x;
    const int lane = tid & 63;

    // ---- stage points; prefill batch ids; init winner slots ----
    for (int j = tid; j < NN; j += FT)
        pts4[j] = make_float4(pb[j * 3 + 0], pb[j * 3 + 1], pb[j * 3 + 2], 0.0f);
    for (int j = tid; j < MM; j += FT) batch_out[b * MM + j] = (float)b;
    if (tid < 3) wsel[tid] = 0ull;
    __syncthreads();

    // ---- all 16 points in registers as 8 packed pairs ----
    // pair j: indices (2j)*FT+tid (.x) and (2j+1)*FT+tid (.y)
    v2f pxv[8], pyv[8], pzv[8], dv[8];
#pragma unroll
    for (int j = 0; j < 8; ++j) {
        const float4 p0 = pts4[(2 * j) * FT + tid];
        const float4 p1 = pts4[(2 * j + 1) * FT + tid];
        pxv[j] = (v2f){p0.x, p1.x};
        pyv[j] = (v2f){p0.y, p1.y};
        pzv[j] = (v2f){p0.z, p1.z};
        dv[j]  = (v2f){INFINITY, INFINITY};
    }

    int   cur = 0;
    float lx = pb[0], ly = pb[1], lz = pb[2];

    for (int s = 0; s < MM; ++s) {
#pragma clang fp contract(off)
        if (tid == 0) {
            samp[b * MM + s] = cur;
            centers_out[((size_t)b * MM + s) * 3 + 0] = lx;
            centers_out[((size_t)b * MM + s) * 3 + 1] = ly;
            centers_out[((size_t)b * MM + s) * 3 + 2] = lz;
        }
        if (s == MM - 1) break;   // last argmax unused by the reference

        // pre-negated center: px + (-lx) is bit-identical to px - lx,
        // and the sign vanishes under squaring
        const v2f nl2x = (v2f){-lx, -lx};
        const v2f nl2y = (v2f){-ly, -ly};
        const v2f nl2z = (v2f){-lz, -lz};

        // ---- phase 1: packed distance update + value-only running max ----
        v2f vmax2 = (v2f){-INFINITY, -INFINITY};
#pragma unroll
        for (int j = 0; j < 8; ++j) {
            const v2f dx = pk_add(pxv[j], nl2x);
            const v2f dy = pk_add(pyv[j], nl2y);
            const v2f dz = pk_add(pzv[j], nl2z);
            // exact ref order: ((dx*dx + dy*dy) + dz*dz), separate mul/add
            const v2f d2 = pk_add(pk_add(pk_mul(dx, dx), pk_mul(dy, dy)),
                                  pk_mul(dz, dz));
            dv[j] = __builtin_elementwise_min(dv[j], d2);   // jnp.minimum, exact
            vmax2 = __builtin_elementwise_max(vmax2, dv[j]);
        }
        const float tv = fmaxf(vmax2.x, vmax2.y);           // thread value max

        // ---- per-thread first-max index: descending cndmask scan ----
        // process high indices first so the lowest matching index wins
        int cand = 0;
#pragma unroll
        for (int j = 7; j >= 0; --j) {
            cand = (dv[j].y == tv) ? (2 * j + 1) * FT + tid : cand;
            cand = (dv[j].x == tv) ? (2 * j) * FT + tid     : cand;
        }

        // ---- pack (value, 8191-idx) u64; wave DPP64 reduce; one atomic ----
        u64 key = (((u64)(unsigned int)__float_as_int(tv)) << 32)
                | (u64)(unsigned int)(8191 - cand);
        DPP64_REDUCE(key)
        const int sl = s % 3;
        if (lane == 63) atomicMax(&wsel[sl], key);
        __syncthreads();

        // all threads broadcast-read the block winner
        const u64 win = wsel[sl];
        // rotate: reset the slot used last step (next used at s+2).
        // safe: this reset is separated from s+2's atomicMax by barrier s+1,
        // and from step s-1's readers by barrier s (program order + lgkmcnt).
        if (tid == 0) wsel[(s + 2) % 3] = 0ull;

        cur = 8191 - (int)(unsigned int)(win & 0xFFFFFFFFull);
        const float4 wp = pts4[cur];                        // broadcast, conflict-free
        lx = wp.x; ly = wp.y; lz = wp.z;
    }
}

// ---------------- Kernel 2: radius-KNN, one wave per center ----------------
#define CAP 256
__global__ __launch_bounds__(256) void knn_kernel(
    const float* __restrict__ pos,
    const int* __restrict__ samp,
    int* __restrict__ nbr,
    int* __restrict__ cntbuf)
{
    const int wave = threadIdx.x >> 6;
    const int lane = threadIdx.x & 63;
    const int c = blockIdx.x * 4 + wave;
    const int b = c >> 11;
    const float* pb = pos + (size_t)b * NN * 3;

    __shared__ float sd2[4][CAP];
    __shared__ int   sid[4][CAP];

    const int ctr = samp[c];
    const float cx = pb[ctr * 3 + 0];
    const float cy = pb[ctr * 3 + 1];
    const float cz = pb[ctr * 3 + 2];
    const float R2 = (float)(0.1 * 0.1);

    int cnt = 0;
    for (int r = 0; r < NN / 64; ++r) {
        const int g = r * 64 + lane;
        float dx = __fsub_rn(cx, pb[g * 3 + 0]);
        float dy = __fsub_rn(cy, pb[g * 3 + 1]);
        float dz = __fsub_rn(cz, pb[g * 3 + 2]);
        float d2 = __fadd_rn(__fadd_rn(__fmul_rn(dx, dx), __fmul_rn(dy, dy)),
                             __fmul_rn(dz, dz));
        const bool pred = (d2 <= R2);
        const unsigned long long mask = __ballot(pred);
        const int before = __popcll(mask & ((1ull << lane) - 1ull));
        if (pred) {
            const int slot = cnt + before;
            if (slot < CAP) { sd2[wave][slot] = d2; sid[wave][slot] = g; }
        }
        cnt += __popcll(mask);
    }
    if (cnt > CAP) cnt = CAP;
    __syncthreads();

    for (int ci = lane; ci < cnt; ci += 64) {
        const float dc = sd2[wave][ci];
        const int   ic = sid[wave][ci];
        int rank = 0;
        for (int j = 0; j < cnt; ++j) {
            const float dj = sd2[wave][j];
            const int   ij = sid[wave][j];
            rank += (dj < dc || (dj == dc && ij < ic)) ? 1 : 0;
        }
        if (rank < KK) nbr[c * KK + rank] = ic;
    }
    if (lane == 0) cntbuf[c] = (cnt < KK) ? cnt : KK;
}

// ---------------- Kernel 3: gather + MLP + max-pool, one wave per center ----
__global__ __launch_bounds__(256) void mlp_kernel(
    const float* __restrict__ x,
    const float* __restrict__ pos,
    const float* __restrict__ W1,
    const float* __restrict__ b1,
    const float* __restrict__ W2,
    const float* __restrict__ b2,
    const int* __restrict__ nbr,
    const int* __restrict__ cntbuf,
    const float* __restrict__ centers,
    float* __restrict__ out)
{
    __shared__ float WT[64 * 68];
    __shared__ float featL[4][32 * 68];

    const int tid = threadIdx.x, wave = tid >> 6, lane = tid & 63;
    const int c = blockIdx.x * 4 + wave;
    const int b = c >> 11;
    const int cnt = cntbuf[c];

    for (int idx = tid; idx < 67 * 64; idx += 256) {
        const int i = idx >> 6, h = idx & 63;
        WT[h * 68 + i] = W1[idx];
    }
    if (tid < 64) WT[tid * 68 + 67] = 0.0f;

    const float ctr0 = centers[c * 3 + 0];
    const float ctr1 = centers[c * 3 + 1];
    const float ctr2 = centers[c * 3 + 2];
    for (int k = 0; k < cnt; ++k) {
        const int j = nbr[c * KK + k];
        featL[wave][k * 68 + lane] = x[((size_t)b * NN + j) * FF + lane];
        if (lane < 3) {
            const float pj = pos[((size_t)b * NN + j) * 3 + lane];
            const float ci = (lane == 0) ? ctr0 : ((lane == 1) ? ctr1 : ctr2);
            featL[wave][k * 68 + 64 + lane] = __fsub_rn(pj, ci);
        }
        if (lane == 3) featL[wave][k * 68 + 67] = 0.0f;
    }
    __syncthreads();

    float wreg[68];
#pragma unroll
    for (int i4 = 0; i4 < 17; ++i4) {
        const float4 v = *(const float4*)&WT[lane * 68 + i4 * 4];
        wreg[i4 * 4 + 0] = v.x; wreg[i4 * 4 + 1] = v.y;
        wreg[i4 * 4 + 2] = v.z; wreg[i4 * 4 + 3] = v.w;
    }
    const float bias1 = b1[lane];
    for (int k = 0; k < cnt; ++k) {
        float acc = bias1;
#pragma unroll
        for (int i4 = 0; i4 < 17; ++i4) {
            const float4 f = *(const float4*)&featL[wave][k * 68 + i4 * 4];
            acc = fmaf(f.x, wreg[i4 * 4 + 0], acc);
            acc = fmaf(f.y, wreg[i4 * 4 + 1], acc);
            acc = fmaf(f.z, wreg[i4 * 4 + 2], acc);
            acc = fmaf(f.w, wreg[i4 * 4 + 3], acc);
        }
        featL[wave][k * 68 + lane] = fmaxf(acc, 0.0f);
    }
    __syncthreads();

    for (int idx = tid; idx < 64 * 64; idx += 256) {
        const int i = idx >> 6, h = idx & 63;
        WT[h * 68 + i] = W2[idx];
    }
    __syncthreads();

#pragma unroll
    for (int i4 = 0; i4 < 16; ++i4) {
        const float4 v = *(const float4*)&WT[lane * 68 + i4 * 4];
        wreg[i4 * 4 + 0] = v.x; wreg[i4 * 4 + 1] = v.y;
        wreg[i4 * 4 + 2] = v.z; wreg[i4 * 4 + 3] = v.w;
    }
    const float bias2 = b2[lane];
    float m = -INFINITY;
    for (int k = 0; k < cnt; ++k) {
        float acc = bias2;
#pragma unroll
        for (int i4 = 0; i4 < 16; ++i4) {
            const float4 f = *(const float4*)&featL[wave][k * 68 + i4 * 4];
            acc = fmaf(f.x, wreg[i4 * 4 + 0], acc);
            acc = fmaf(f.y, wreg[i4 * 4 + 1], acc);
            acc = fmaf(f.z, wreg[i4 * 4 + 2], acc);
            acc = fmaf(f.w, wreg[i4 * 4 + 3], acc);
        }
        m = fmaxf(m, fmaxf(acc, 0.0f));
    }
    out[(size_t)c * HH + lane] = (cnt > 0) ? m : 0.0f;
}

extern "C" void kernel_launch(void* const* d_in, const int* in_sizes, int n_in,
                              void* d_out, int out_size, void* d_ws, size_t ws_size,
                              hipStream_t stream) {
    const float* x   = (const float*)d_in[0];
    const float* pos = (const float*)d_in[1];
    const float* W1  = (const float*)d_in[3];
    const float* b1  = (const float*)d_in[4];
    const float* W2  = (const float*)d_in[5];
    const float* b2  = (const float*)d_in[6];

    float* out         = (float*)d_out;
    float* centers_out = out + (size_t)NB * MM * HH;
    float* batch_out   = centers_out + (size_t)NB * MM * 3;

    char* ws = (char*)d_ws;
    int* samp   = (int*)ws;
    int* cntbuf = (int*)(ws + (size_t)NB * MM * 4);
    int* nbr    = (int*)(ws + (size_t)2 * NB * MM * 4);

    fps_kernel<<<NB, FT, 0, stream>>>(pos, samp, centers_out, batch_out);
    knn_kernel<<<(NB * MM) / 4, 256, 0, stream>>>(pos, samp, nbr, cntbuf);
    mlp_kernel<<<(NB * MM) / 4, 256, 0, stream>>>(x, pos, W1, b1, W2, b2,
                                                  nbr, cntbuf, centers_out, out);
}